// Round 10
// baseline (58.440 us; speedup 1.0000x reference)
//
#include <hip/hip_runtime.h>
#include <math.h>

#define NFFT   1024
#define FREQ   513
#define FRAMES 256
#define SIGLEN 66560          // 256*256 + 1024
#define NB     4
#define BFT    (NB * FREQ * FRAMES)   // 525312
#define NWAVE  8               // waves per block (n-loop split factor)
#define NTHR   (64 * NWAVE)    // 512
#define NCHUNK 9               // ceil(513/64)
#define UNITS  (NCHUNK * FRAMES)      // 2304 blocks, 1 unit each (LPT order)

// ---------------------------------------------------------------------------
// perm = argsort(theta) DESCENDING, stable (O(F^2) rank). Needs 2052 B of ws.
// ---------------------------------------------------------------------------
__global__ __launch_bounds__(1024)
void dstft_perm(const float* __restrict__ raw_win, int* __restrict__ perm)
{
    __shared__ float th[FREQ];
    const int tid = threadIdx.x;
    if (tid < FREQ)
        th[tid] = 10.0f + 1014.0f / (1.0f + expf(-raw_win[tid]));
    __syncthreads();
    if (tid < FREQ) {
        const float ti = th[tid];
        int r = 0;
        for (int j = 0; j < FREQ; ++j) {
            const float tj = th[j];
            r += (tj > ti) || (tj == ti && j < tid);   // descending, stable
        }
        perm[r] = tid;
    }
}

__device__ __forceinline__ float sigmoid_f32(float v)
{
    if (v >= 0.0f) {
        return 1.0f / (1.0f + expf(-v));
    } else {
        const float e = expf(v);
        return e / (1.0f + e);
    }
}

__device__ __forceinline__ float rfl_f32(float v)
{
    return __int_as_float(__builtin_amdgcn_readfirstlane(__float_as_int(v)));
}

// ---------------------------------------------------------------------------
// Block = 8 waves = 512 thr, ONE unit (t, 64-f chunk) per block. 2304 blocks
// in descending-theta (LPT) order = 2.25 residency rounds -> HW queue
// backfills as blocks retire. Wave q takes the q-th eighth of the support.
// LDS: xlds (16 KB) aliased with part (18 KB), sync-separated.
// Epilogue parallel over 4 waves (thread = lane x batch).
// ---------------------------------------------------------------------------
__global__ __launch_bounds__(NTHR)
void dstft_main(const float* __restrict__ x,
                const float* __restrict__ raw_win,
                const float* __restrict__ raw_hop,
                const int* __restrict__ perm,      // may be null (unsorted)
                float* __restrict__ out, int out_size, int stft_mode)
{
    const int tid  = threadIdx.x;
    const int lane = tid & 63;
    const int q    = tid >> 6;               // wave id = n-segment id

    __shared__ __align__(16) unsigned char smem[NWAVE * 64 * 9 * 4]; // 18.4KB
    float4* xlds = reinterpret_cast<float4*>(smem);
    float (*part)[64][9] = reinterpret_cast<float (*)[64][9]>(smem);

    const int u     = (int)blockIdx.x;
    const int chunk = u >> 8;                // 0..8 (desc-theta order)
    const int t     = u & 255;
    const int spos  = chunk * 64 + lane;
    const bool active = (spos < FREQ);

    int f = 0;
    if (active) {
        f = perm ? perm[spos] : spos;
        f = (f < 0) ? 0 : ((f > FREQ - 1) ? (FREQ - 1) : f);
    }
    const float theta = active
        ? (10.0f + sigmoid_f32(raw_win[f]) * 1014.0f)
        : 10.0f;

    // wave-wide max theta -> SGPR
    float tmaxv = theta;
#pragma unroll
    for (int s = 32; s; s >>= 1)
        tmaxv = fmaxf(tmaxv, __shfl_xor(tmaxv, s, 64));
    const float tmax = rfl_f32(tmaxv);

    // pos/floor: f32-canonical replication of the reference (uniform)
    const float hop = 1.0f + sigmoid_f32(raw_hop[0]) * 255.0f;
    float pos = (float)t * hop;
    pos = fminf(fmaxf(pos, 0.0f), 65536.0f);
    const float fl   = floorf(pos);
    const int   base = __builtin_amdgcn_readfirstlane((int)fl);
    const float c    = rfl_f32(511.5f + (pos - fl));

    int lo = (int)floorf(c - 0.5f * tmax);
    int hi = (int)ceilf (c + 0.5f * tmax);
    lo = lo > 0 ? lo : 0;
    hi = hi < (NFFT - 1) ? hi : (NFFT - 1);
    int cnt = hi - lo + 1;
    cnt = cnt < 0 ? 0 : (cnt > NFFT ? NFFT : cnt);
    lo  = __builtin_amdgcn_readfirstlane(lo);
    cnt = __builtin_amdgcn_readfirstlane(cnt);

    // ---- stage x tile [lo, lo+cnt) into LDS (coalesced) ----
    for (int n = lo + tid; n < lo + cnt; n += NTHR) {
        float4 v;
        v.x = x[base + n];
        v.y = x[base + n + SIGLEN];
        v.z = x[base + n + 2 * SIGLEN];
        v.w = x[base + n + 3 * SIGLEN];
        xlds[n - lo] = v;
    }
    __syncthreads();

    const int s0     = lo + (cnt * q) / NWAVE;
    const int s1     = lo + (cnt * (q + 1)) / NWAVE;
    const int segcnt = s1 - s0;

    const float invth = 1.0f / theta;
    float r = ((float)s0 - c) * invth;       // window arg, revolutions

    // phasor init at n=s0 and step: exact int reduction + hw trig (rev)
    const float sdr = (float)f * (1.0f / 1024.0f);
    const float cd  = __builtin_amdgcn_cosf(sdr);
    const float sd  = __builtin_amdgcn_sinf(sdr);
    int m0 = (f * s0) & (NFFT - 1);
    m0 = (m0 >= 512) ? (m0 - 1024) : m0;
    const float p0 = (float)m0 * (1.0f / 1024.0f);
    float ca = __builtin_amdgcn_cosf(p0);
    float sa = __builtin_amdgcn_sinf(p0);

    float re0 = 0.f, re1 = 0.f, re2 = 0.f, re3 = 0.f;
    float sm0 = 0.f, sm1 = 0.f, sm2 = 0.f, sm3 = 0.f;

    const float4* __restrict__ xp = &xlds[s0 - lo];
#pragma unroll 4
    for (int i = 0; i < segcnt; ++i) {
        // med3 clamp; cos(2*pi*(+-0.5)) = -1 -> w = 0 outside support
        const float rc = __builtin_amdgcn_fmed3f(r, -0.5f, 0.5f);
        const float w  = fmaf(0.5f, __builtin_amdgcn_cosf(rc), 0.5f);
        const float wc  = w * ca;
        const float wsn = w * sa;
        const float4 v = xp[i];                        // ds_read_b128
        re0 = fmaf(v.x, wc, re0);  sm0 = fmaf(v.x, wsn, sm0);
        re1 = fmaf(v.y, wc, re1);  sm1 = fmaf(v.y, wsn, sm1);
        re2 = fmaf(v.z, wc, re2);  sm2 = fmaf(v.z, wsn, sm2);
        re3 = fmaf(v.w, wc, re3);  sm3 = fmaf(v.w, wsn, sm3);
        const float nca = fmaf(ca, cd, -(sa * sd));
        const float nsa = fmaf(sa, cd,   ca * sd);
        ca = nca; sa = nsa;
        r += invth;
    }

    // ---- cross-wave combine; part aliases xlds, fence reads first ----
    __syncthreads();
    part[q][lane][0] = re0;  part[q][lane][1] = re1;
    part[q][lane][2] = re2;  part[q][lane][3] = re3;
    part[q][lane][4] = sm0;  part[q][lane][5] = sm1;
    part[q][lane][6] = sm2;  part[q][lane][7] = sm3;
    __syncthreads();

    // ---- epilogue: 4 waves in parallel, thread = (lane, batch) ----
    if (tid < 256 && active) {
        const int b = tid >> 6;              // batch 0..3
        float res = 0.f, sms = 0.f;
#pragma unroll
        for (int p = 0; p < NWAVE; ++p) {
            res += part[p][lane][b];
            sms += part[p][lane][4 + b];
        }
        const float re = res;
        const float im = -sms;
        const int idx = b * (FREQ * FRAMES) + f * FRAMES + t;
        if (idx < out_size)
            out[idx] = sqrtf(fmaf(re, re, im * im)) + 1e-12f;   // spec
        if (stft_mode == 2) {
            if (BFT + 2 * idx + 1 < out_size) {
                out[BFT + 2 * idx]     = re;
                out[BFT + 2 * idx + 1] = im;
            }
        } else {
            if (BFT + idx < out_size)
                out[BFT + idx] = re;         // complex stored as f32 real
        }
    }
}

// ---------------------------------------------------------------------------
extern "C" void kernel_launch(void* const* d_in, const int* in_sizes, int n_in,
                              void* d_out, int out_size, void* d_ws, size_t ws_size,
                              hipStream_t stream)
{
    const float* x       = (const float*)d_in[0];
    const float* raw_win = (const float*)d_in[1];
    const float* raw_hop = (const float*)d_in[2];
    float* out = (float*)d_out;

    int* perm = nullptr;
    if (d_ws != nullptr && ws_size >= 4096) {
        perm = (int*)d_ws;
        dstft_perm<<<1, 1024, 0, stream>>>(raw_win, perm);
    }
    const int stft_mode = (out_size >= 3 * BFT) ? 2 : 1;
    dstft_main<<<UNITS, NTHR, 0, stream>>>(
        x, raw_win, raw_hop, perm, out, out_size, stft_mode);
}